// Round 3
// baseline (248.387 us; speedup 1.0000x reference)
//
#include <hip/hip_runtime.h>
#include <stdint.h>

// Causal GQA attention fwd, B=2 T=2048 H=32 HKV=8 D=128, fp32 in/out, bf16 MFMA compute.
//
// Round 3: zero-shuffle P (kv-axis permuted identically in V^T pre-pass and P packing,
// so QK^T output feeds PV's A-fragment in-register), Plds removed (LDS 32KB -> 5 blocks/CU),
// complementary qtile pairing for CU load balance.
//
//   cvt_k:  K fp32 [B,T,8,128] -> Kb bf16 [B,8,T,128], 16B-slot s stored at s^(t&7)
//   cvt_v:  V fp32 [B,T,8,128] -> VTb bf16 tiled [B,8,tile(64)][d(128)][slots], where
//           B-frag slot g elem e holds kv pi(8g+e) = (e<4 ? 4g+e : 16+4g+e-4); slot
//           stored at g^((d>>1)&3) for conflict-free ds_read_b128.
//   attn:   1024 blocks x 256 thr (4 waves). Block = (b, h, 128 q rows); wave = 32 q rows.
//           KV tiles of 32, double-buffered LDS staged via global_load_lds width=16.
//           QK^T swapped: S^T = mfma(K-frag, Q-frag)  (lane: q=lane&15, kv=(lane>>4)*4+reg)
//           Online softmax log2-domain, T13 defer-rescale (THR=8), diagonal-only masking.

typedef __attribute__((ext_vector_type(8))) __bf16 bf16x8;
typedef __attribute__((ext_vector_type(4))) float f32x4;

#define QSCALE (0.08838834764831845f * 1.4426950408889634f)

// ---------------- pre-pass: K convert + swizzle ----------------
__global__ __launch_bounds__(256) void cvt_k(const float* __restrict__ k,
                                             unsigned short* __restrict__ kb) {
    unsigned tid = blockIdx.x * 256u + threadIdx.x;
    unsigned s = tid & 15u;
    unsigned h = (tid >> 4) & 7u;
    unsigned t = (tid >> 7) & 2047u;
    unsigned b = tid >> 18;
    const float4* src = (const float4*)(k + (size_t)tid * 8u);
    float4 f0 = src[0], f1 = src[1];
    bf16x8 r;
    r[0] = (__bf16)f0.x; r[1] = (__bf16)f0.y; r[2] = (__bf16)f0.z; r[3] = (__bf16)f0.w;
    r[4] = (__bf16)f1.x; r[5] = (__bf16)f1.y; r[6] = (__bf16)f1.z; r[7] = (__bf16)f1.w;
    size_t o = ((size_t)((b * 8u + h) * 2048u + t) * 16u + (s ^ (t & 7u))) * 8u;
    *(bf16x8*)(kb + o) = r;
}

// ---------------- pre-pass: V convert + transpose + kv-permute + tile ----------------
__global__ __launch_bounds__(256) void cvt_v(const float* __restrict__ v,
                                             unsigned short* __restrict__ vtb) {
    unsigned tid = blockIdx.x * 256u + threadIdx.x;
    unsigned d = tid & 127u;            // fast-varying => coalesced reads
    unsigned slot = (tid >> 7) & 3u;    // B-fragment group g
    unsigned tile = (tid >> 9) & 63u;
    unsigned h = (tid >> 15) & 7u;
    unsigned b = tid >> 18;
    const float* src = v + ((size_t)(b * 2048u + tile * 32u) * 8u + h) * 128u + d;
    bf16x8 r;
#pragma unroll
    for (int jj = 0; jj < 8; ++jj) {
        unsigned kvl = (jj < 4) ? (slot * 4u + jj) : (12u + slot * 4u + jj); // pi(8g+e)
        r[jj] = (__bf16)src[(size_t)kvl * 1024u];
    }
    size_t o = (((size_t)((b * 8u + h) * 64u + tile) * 128u + d) * 4u
                + (slot ^ ((d >> 1) & 3u))) * 8u;
    *(bf16x8*)(vtb + o) = r;
}

// ---------------- main attention kernel ----------------
__device__ inline void load16_lds(const void* g, void* l) {
    __builtin_amdgcn_global_load_lds(
        (__attribute__((address_space(1))) void*)(g),
        (__attribute__((address_space(3))) void*)(l), 16, 0, 0);
}

__global__ __launch_bounds__(256, 4) void attn_fwd(const float* __restrict__ qg,
                                                   const unsigned short* __restrict__ kb,
                                                   const unsigned short* __restrict__ vtb,
                                                   float* __restrict__ outg) {
    __shared__ __align__(16) unsigned short Klds[2][32 * 128];   // 16 KB
    __shared__ __align__(16) unsigned short Vlds[2][128 * 32];   // 16 KB

    // Decode: bid&7 = XCD; per XCD, blocks ii and ii+32 get complementary qtiles
    // (15-q and q) so each CU's 4 resident blocks sum to uniform work.
    int bid = blockIdx.x;
    int x = bid & 7, ii = bid >> 3;            // ii: 0..127
    int g = x + 8 * (ii >> 6);                 // kv-group 0..15
    int j = ii & 63;
    int b = g >> 3, kvh = g & 7;
    int grp = j >> 4;                          // 0..3 -> q-head within kv group
    int qsel = j & 15;
    int h = kvh * 4 + grp;
    int qtile = (grp & 2) ? qsel : 15 - qsel;  // complementary across ii+-32
    int q0 = qtile * 128;

    int lane = threadIdx.x & 63;
    int w = threadIdx.x >> 6;
    int lq = lane & 15;
    int gq = lane >> 4;
    int qbase = q0 + w * 32;

    const unsigned short* kTile = kb + (size_t)(b * 8 + kvh) * 2048u * 128u;
    const unsigned short* vTile = vtb + (size_t)(b * 8 + kvh) * 64u * 4096u;
    int nt = 4 * (qtile + 1);

    auto stage = [&](int t, int buf) {
        const char* ks = (const char*)(kTile + (size_t)t * 4096u);
        const char* vs = (const char*)(vTile + (size_t)t * 4096u);
#pragma unroll
        for (int c2 = 0; c2 < 2; ++c2) {
            int call = w * 2 + c2;
            load16_lds(ks + call * 1024 + lane * 16, &Klds[buf][call * 512]);
            load16_lds(vs + call * 1024 + lane * 16, &Vlds[buf][call * 512]);
        }
    };

    stage(0, 0);

    bf16x8 qf[2][4];
#pragma unroll
    for (int half = 0; half < 2; ++half) {
        const float* qb = qg + ((size_t)(b * 2048 + qbase + half * 16 + lq) * 32u + h) * 128u;
#pragma unroll
        for (int c = 0; c < 4; ++c) {
            const float4* p4 = (const float4*)(qb + c * 32 + gq * 8);
            float4 f0 = p4[0], f1 = p4[1];
            qf[half][c][0] = (__bf16)(f0.x * QSCALE); qf[half][c][1] = (__bf16)(f0.y * QSCALE);
            qf[half][c][2] = (__bf16)(f0.z * QSCALE); qf[half][c][3] = (__bf16)(f0.w * QSCALE);
            qf[half][c][4] = (__bf16)(f1.x * QSCALE); qf[half][c][5] = (__bf16)(f1.y * QSCALE);
            qf[half][c][6] = (__bf16)(f1.z * QSCALE); qf[half][c][7] = (__bf16)(f1.w * QSCALE);
        }
    }

    f32x4 zero4 = {0.f, 0.f, 0.f, 0.f};
    f32x4 acc[2][8];
#pragma unroll
    for (int half = 0; half < 2; ++half)
#pragma unroll
        for (int dt = 0; dt < 8; ++dt) acc[half][dt] = zero4;
    float mrun[2] = {-1e30f, -1e30f}, lrun[2] = {0.f, 0.f};

    for (int t = 0; t < nt; ++t) {
        asm volatile("s_waitcnt vmcnt(0)" ::: "memory");
        __syncthreads();
        int buf = t & 1;
        if (t + 1 < nt) stage(t + 1, buf ^ 1);
        int kv0 = t * 32;
        if (kv0 <= qbase + 31) {                         // wave-uniform causal skip
            // ---- QK^T: K-frags shared by both q-halves
            f32x4 st[2][2];
            st[0][0] = zero4; st[0][1] = zero4; st[1][0] = zero4; st[1][1] = zero4;
            int soff = lq & 7;
#pragma unroll
            for (int c = 0; c < 4; ++c) {
                bf16x8 kf0 = *(const bf16x8*)&Klds[buf][lq * 128 + (((c * 4 + gq) ^ soff) << 3)];
                bf16x8 kf1 = *(const bf16x8*)&Klds[buf][(16 + lq) * 128 + (((c * 4 + gq) ^ soff) << 3)];
                st[0][0] = __builtin_amdgcn_mfma_f32_16x16x32_bf16(kf0, qf[0][c], st[0][0], 0, 0, 0);
                st[1][0] = __builtin_amdgcn_mfma_f32_16x16x32_bf16(kf0, qf[1][c], st[1][0], 0, 0, 0);
                st[0][1] = __builtin_amdgcn_mfma_f32_16x16x32_bf16(kf1, qf[0][c], st[0][1], 0, 0, 0);
                st[1][1] = __builtin_amdgcn_mfma_f32_16x16x32_bf16(kf1, qf[1][c], st[1][1], 0, 0, 0);
            }
            // ---- mask (diagonal tiles only) + per-row max
            float vals[2][8], mx[2];
            bool need_mask = (kv0 + 31 > qbase);         // wave-uniform
#pragma unroll
            for (int half = 0; half < 2; ++half) {
                float m = -1e30f;
                if (need_mask) {
                    int qr = qbase + half * 16 + lq;
#pragma unroll
                    for (int r = 0; r < 4; ++r) {
                        float s0 = (kv0 + gq * 4 + r <= qr) ? st[half][0][r] : -1e30f;
                        float s1 = (kv0 + 16 + gq * 4 + r <= qr) ? st[half][1][r] : -1e30f;
                        vals[half][r] = s0; vals[half][4 + r] = s1;
                        m = fmaxf(m, fmaxf(s0, s1));
                    }
                } else {
#pragma unroll
                    for (int r = 0; r < 4; ++r) {
                        float s0 = st[half][0][r], s1 = st[half][1][r];
                        vals[half][r] = s0; vals[half][4 + r] = s1;
                        m = fmaxf(m, fmaxf(s0, s1));
                    }
                }
                m = fmaxf(m, __shfl_xor(m, 16));
                m = fmaxf(m, __shfl_xor(m, 32));
                mx[half] = m;
            }
            // ---- T13 defer-rescale: only rescale when max grew by > 8 (log2 domain)
            if (!__all(mx[0] <= mrun[0] + 8.f && mx[1] <= mrun[1] + 8.f)) {
#pragma unroll
                for (int half = 0; half < 2; ++half) {
                    float mn = fmaxf(mrun[half], mx[half]);
                    float fac = exp2f(mrun[half] - mn);
                    lrun[half] *= fac; mrun[half] = mn;
                    float fr0 = __shfl(fac, gq * 4);
                    float fr1 = __shfl(fac, gq * 4 + 1);
                    float fr2 = __shfl(fac, gq * 4 + 2);
                    float fr3 = __shfl(fac, gq * 4 + 3);
#pragma unroll
                    for (int dt = 0; dt < 8; ++dt) {
                        acc[half][dt][0] *= fr0; acc[half][dt][1] *= fr1;
                        acc[half][dt][2] *= fr2; acc[half][dt][3] *= fr3;
                    }
                }
            }
            // ---- exp2, row-sum, pack P in-register (kv order matches permuted V^T)
            bf16x8 pf[2];
#pragma unroll
            for (int half = 0; half < 2; ++half) {
                float ps = 0.f;
#pragma unroll
                for (int r = 0; r < 4; ++r) {
                    float v0 = exp2f(vals[half][r] - mrun[half]);
                    float v1 = exp2f(vals[half][4 + r] - mrun[half]);
                    ps += v0 + v1;
                    pf[half][r] = (__bf16)v0;       // kv = 4*gq + r
                    pf[half][4 + r] = (__bf16)v1;   // kv = 16 + 4*gq + r
                }
                ps += __shfl_xor(ps, 16);
                ps += __shfl_xor(ps, 32);
                lrun[half] += ps;
            }
            // ---- PV: V-frags shared by both q-halves, P straight from registers
#pragma unroll
            for (int dt = 0; dt < 8; ++dt) {
                int d = dt * 16 + lq;
                bf16x8 vf = *(const bf16x8*)&Vlds[buf][d * 32 + ((gq ^ ((d >> 1) & 3)) << 3)];
                acc[0][dt] = __builtin_amdgcn_mfma_f32_16x16x32_bf16(pf[0], vf, acc[0][dt], 0, 0, 0);
                acc[1][dt] = __builtin_amdgcn_mfma_f32_16x16x32_bf16(pf[1], vf, acc[1][dt], 0, 0, 0);
            }
        }
    }

    // ---- epilogue
#pragma unroll
    for (int half = 0; half < 2; ++half) {
        float il = 1.0f / lrun[half];
        float i0 = __shfl(il, gq * 4);
        float i1 = __shfl(il, gq * 4 + 1);
        float i2 = __shfl(il, gq * 4 + 2);
        float i3 = __shfl(il, gq * 4 + 3);
        float* ob = outg + (size_t)(b * 2048 + qbase + half * 16) * 4096u + h * 128;
#pragma unroll
        for (int dt = 0; dt < 8; ++dt) {
            ob[(size_t)(gq * 4 + 0) * 4096u + dt * 16 + lq] = acc[half][dt][0] * i0;
            ob[(size_t)(gq * 4 + 1) * 4096u + dt * 16 + lq] = acc[half][dt][1] * i1;
            ob[(size_t)(gq * 4 + 2) * 4096u + dt * 16 + lq] = acc[half][dt][2] * i2;
            ob[(size_t)(gq * 4 + 3) * 4096u + dt * 16 + lq] = acc[half][dt][3] * i3;
        }
    }
}

extern "C" void kernel_launch(void* const* d_in, const int* in_sizes, int n_in,
                              void* d_out, int out_size, void* d_ws, size_t ws_size,
                              hipStream_t stream) {
    const float* q = (const float*)d_in[0];
    const float* k = (const float*)d_in[1];
    const float* v = (const float*)d_in[2];
    float* out = (float*)d_out;
    unsigned short* kbuf = (unsigned short*)d_ws;                    // 8 MB bf16 K
    unsigned short* vbuf = kbuf + (size_t)2 * 8 * 2048 * 128;        // 8 MB bf16 V^T (tiled)
    cvt_k<<<2048, 256, 0, stream>>>(k, kbuf);
    cvt_v<<<2048, 256, 0, stream>>>(v, vbuf);
    attn_fwd<<<1024, 256, 0, stream>>>(q, kbuf, vbuf, out);
}

// Round 4
// 176.801 us; speedup vs baseline: 1.4049x; 1.4049x over previous
//
#include <hip/hip_runtime.h>
#include <stdint.h>

// Causal GQA attention fwd, B=2 T=2048 H=32 HKV=8 D=128, fp32 in/out, bf16 MFMA compute.
//
// Round 4: round-3 structure (zero-shuffle P via kv-permuted V^T, 32KB LDS, complementary
// qtile pairing) with spill fix: __launch_bounds__(256,3) (round-3's (256,4) capped the
// unified file at 128 regs -> 64 arch VGPRs -> ~60 regs spilled -> +126MB scratch traffic).
// Also mask/exp2 in place (no vals[] array) to cut arch-reg pressure.
//
//   cvt_k:  K fp32 [B,T,8,128] -> Kb bf16 [B,8,T,128], 16B-slot s stored at s^(t&7)
//   cvt_v:  V fp32 [B,T,8,128] -> VTb bf16 tiled [B,8,tile(64)][d(128)][slots], where
//           B-frag slot g elem e holds kv pi(8g+e) = (e<4 ? 4g+e : 16+4g+e-4); slot
//           stored at g^((d>>1)&3) for conflict-free ds_read_b128.
//   attn:   1024 blocks x 256 thr (4 waves). Block = (b, h, 128 q rows); wave = 32 q rows.
//           KV tiles of 32, double-buffered LDS staged via global_load_lds width=16.
//           QK^T swapped: S^T = mfma(K-frag, Q-frag)  (lane: q=lane&15, kv=(lane>>4)*4+reg)
//           Online softmax log2-domain, T13 defer-rescale (THR=8), diagonal-only masking.

typedef __attribute__((ext_vector_type(8))) __bf16 bf16x8;
typedef __attribute__((ext_vector_type(4))) float f32x4;

#define QSCALE (0.08838834764831845f * 1.4426950408889634f)

// ---------------- pre-pass: K convert + swizzle ----------------
__global__ __launch_bounds__(256) void cvt_k(const float* __restrict__ k,
                                             unsigned short* __restrict__ kb) {
    unsigned tid = blockIdx.x * 256u + threadIdx.x;
    unsigned s = tid & 15u;
    unsigned h = (tid >> 4) & 7u;
    unsigned t = (tid >> 7) & 2047u;
    unsigned b = tid >> 18;
    const float4* src = (const float4*)(k + (size_t)tid * 8u);
    float4 f0 = src[0], f1 = src[1];
    bf16x8 r;
    r[0] = (__bf16)f0.x; r[1] = (__bf16)f0.y; r[2] = (__bf16)f0.z; r[3] = (__bf16)f0.w;
    r[4] = (__bf16)f1.x; r[5] = (__bf16)f1.y; r[6] = (__bf16)f1.z; r[7] = (__bf16)f1.w;
    size_t o = ((size_t)((b * 8u + h) * 2048u + t) * 16u + (s ^ (t & 7u))) * 8u;
    *(bf16x8*)(kb + o) = r;
}

// ---------------- pre-pass: V convert + transpose + kv-permute + tile ----------------
__global__ __launch_bounds__(256) void cvt_v(const float* __restrict__ v,
                                             unsigned short* __restrict__ vtb) {
    unsigned tid = blockIdx.x * 256u + threadIdx.x;
    unsigned d = tid & 127u;            // fast-varying => coalesced reads
    unsigned slot = (tid >> 7) & 3u;    // B-fragment group g
    unsigned tile = (tid >> 9) & 63u;
    unsigned h = (tid >> 15) & 7u;
    unsigned b = tid >> 18;
    const float* src = v + ((size_t)(b * 2048u + tile * 32u) * 8u + h) * 128u + d;
    bf16x8 r;
#pragma unroll
    for (int jj = 0; jj < 8; ++jj) {
        unsigned kvl = (jj < 4) ? (slot * 4u + jj) : (12u + slot * 4u + jj); // pi(8g+e)
        r[jj] = (__bf16)src[(size_t)kvl * 1024u];
    }
    size_t o = (((size_t)((b * 8u + h) * 64u + tile) * 128u + d) * 4u
                + (slot ^ ((d >> 1) & 3u))) * 8u;
    *(bf16x8*)(vtb + o) = r;
}

// ---------------- main attention kernel ----------------
__device__ inline void load16_lds(const void* g, void* l) {
    __builtin_amdgcn_global_load_lds(
        (__attribute__((address_space(1))) void*)(g),
        (__attribute__((address_space(3))) void*)(l), 16, 0, 0);
}

__global__ __launch_bounds__(256, 3) void attn_fwd(const float* __restrict__ qg,
                                                   const unsigned short* __restrict__ kb,
                                                   const unsigned short* __restrict__ vtb,
                                                   float* __restrict__ outg) {
    __shared__ __align__(16) unsigned short Klds[2][32 * 128];   // 16 KB
    __shared__ __align__(16) unsigned short Vlds[2][128 * 32];   // 16 KB

    // Decode: bid&7 = XCD; per XCD, complementary qtiles across head-groups so each
    // CU's resident blocks sum to uniform work.
    int bid = blockIdx.x;
    int x = bid & 7, ii = bid >> 3;            // ii: 0..127
    int g = x + 8 * (ii >> 6);                 // kv-group 0..15
    int j = ii & 63;
    int b = g >> 3, kvh = g & 7;
    int grp = j >> 4;                          // 0..3 -> q-head within kv group
    int qsel = j & 15;
    int h = kvh * 4 + grp;
    int qtile = (grp & 2) ? qsel : 15 - qsel;  // complementary pairing
    int q0 = qtile * 128;

    int lane = threadIdx.x & 63;
    int w = threadIdx.x >> 6;
    int lq = lane & 15;
    int gq = lane >> 4;
    int qbase = q0 + w * 32;

    const unsigned short* kTile = kb + (size_t)(b * 8 + kvh) * 2048u * 128u;
    const unsigned short* vTile = vtb + (size_t)(b * 8 + kvh) * 64u * 4096u;
    int nt = 4 * (qtile + 1);

    auto stage = [&](int t, int buf) {
        const char* ks = (const char*)(kTile + (size_t)t * 4096u);
        const char* vs = (const char*)(vTile + (size_t)t * 4096u);
#pragma unroll
        for (int c2 = 0; c2 < 2; ++c2) {
            int call = w * 2 + c2;
            load16_lds(ks + call * 1024 + lane * 16, &Klds[buf][call * 512]);
            load16_lds(vs + call * 1024 + lane * 16, &Vlds[buf][call * 512]);
        }
    };

    stage(0, 0);

    bf16x8 qf[2][4];
#pragma unroll
    for (int half = 0; half < 2; ++half) {
        const float* qb = qg + ((size_t)(b * 2048 + qbase + half * 16 + lq) * 32u + h) * 128u;
#pragma unroll
        for (int c = 0; c < 4; ++c) {
            const float4* p4 = (const float4*)(qb + c * 32 + gq * 8);
            float4 f0 = p4[0], f1 = p4[1];
            qf[half][c][0] = (__bf16)(f0.x * QSCALE); qf[half][c][1] = (__bf16)(f0.y * QSCALE);
            qf[half][c][2] = (__bf16)(f0.z * QSCALE); qf[half][c][3] = (__bf16)(f0.w * QSCALE);
            qf[half][c][4] = (__bf16)(f1.x * QSCALE); qf[half][c][5] = (__bf16)(f1.y * QSCALE);
            qf[half][c][6] = (__bf16)(f1.z * QSCALE); qf[half][c][7] = (__bf16)(f1.w * QSCALE);
        }
    }

    f32x4 zero4 = {0.f, 0.f, 0.f, 0.f};
    f32x4 acc[2][8];
#pragma unroll
    for (int half = 0; half < 2; ++half)
#pragma unroll
        for (int dt = 0; dt < 8; ++dt) acc[half][dt] = zero4;
    float mrun[2] = {-1e30f, -1e30f}, lrun[2] = {0.f, 0.f};

    for (int t = 0; t < nt; ++t) {
        asm volatile("s_waitcnt vmcnt(0)" ::: "memory");
        __syncthreads();
        int buf = t & 1;
        if (t + 1 < nt) stage(t + 1, buf ^ 1);
        int kv0 = t * 32;
        if (kv0 <= qbase + 31) {                         // wave-uniform causal skip
            // ---- QK^T: K-frags shared by both q-halves
            f32x4 st[2][2];
            st[0][0] = zero4; st[0][1] = zero4; st[1][0] = zero4; st[1][1] = zero4;
            int soff = lq & 7;
#pragma unroll
            for (int c = 0; c < 4; ++c) {
                bf16x8 kf0 = *(const bf16x8*)&Klds[buf][lq * 128 + (((c * 4 + gq) ^ soff) << 3)];
                bf16x8 kf1 = *(const bf16x8*)&Klds[buf][(16 + lq) * 128 + (((c * 4 + gq) ^ soff) << 3)];
                st[0][0] = __builtin_amdgcn_mfma_f32_16x16x32_bf16(kf0, qf[0][c], st[0][0], 0, 0, 0);
                st[1][0] = __builtin_amdgcn_mfma_f32_16x16x32_bf16(kf0, qf[1][c], st[1][0], 0, 0, 0);
                st[0][1] = __builtin_amdgcn_mfma_f32_16x16x32_bf16(kf1, qf[0][c], st[0][1], 0, 0, 0);
                st[1][1] = __builtin_amdgcn_mfma_f32_16x16x32_bf16(kf1, qf[1][c], st[1][1], 0, 0, 0);
            }
            // ---- mask (diagonal tiles only, in place) + per-row max
            float mx[2];
            bool need_mask = (kv0 + 31 > qbase);         // wave-uniform
            if (need_mask) {
#pragma unroll
                for (int half = 0; half < 2; ++half) {
                    int qr = qbase + half * 16 + lq;
#pragma unroll
                    for (int r = 0; r < 4; ++r) {
                        if (kv0 + gq * 4 + r > qr)      st[half][0][r] = -1e30f;
                        if (kv0 + 16 + gq * 4 + r > qr) st[half][1][r] = -1e30f;
                    }
                }
            }
#pragma unroll
            for (int half = 0; half < 2; ++half) {
                float m = -1e30f;
#pragma unroll
                for (int r = 0; r < 4; ++r)
                    m = fmaxf(m, fmaxf(st[half][0][r], st[half][1][r]));
                m = fmaxf(m, __shfl_xor(m, 16));
                m = fmaxf(m, __shfl_xor(m, 32));
                mx[half] = m;
            }
            // ---- T13 defer-rescale: only rescale when max grew by > 8 (log2 domain)
            if (!__all(mx[0] <= mrun[0] + 8.f && mx[1] <= mrun[1] + 8.f)) {
#pragma unroll
                for (int half = 0; half < 2; ++half) {
                    float mn = fmaxf(mrun[half], mx[half]);
                    float fac = exp2f(mrun[half] - mn);
                    lrun[half] *= fac; mrun[half] = mn;
                    float fr0 = __shfl(fac, gq * 4);
                    float fr1 = __shfl(fac, gq * 4 + 1);
                    float fr2 = __shfl(fac, gq * 4 + 2);
                    float fr3 = __shfl(fac, gq * 4 + 3);
#pragma unroll
                    for (int dt = 0; dt < 8; ++dt) {
                        acc[half][dt][0] *= fr0; acc[half][dt][1] *= fr1;
                        acc[half][dt][2] *= fr2; acc[half][dt][3] *= fr3;
                    }
                }
            }
            // ---- exp2 in place, row-sum, pack P in-register (kv order matches permuted V^T)
            bf16x8 pf[2];
#pragma unroll
            for (int half = 0; half < 2; ++half) {
                float ps = 0.f;
#pragma unroll
                for (int r = 0; r < 4; ++r) {
                    float v0 = exp2f(st[half][0][r] - mrun[half]);
                    float v1 = exp2f(st[half][1][r] - mrun[half]);
                    ps += v0 + v1;
                    pf[half][r] = (__bf16)v0;       // kv = 4*gq + r
                    pf[half][4 + r] = (__bf16)v1;   // kv = 16 + 4*gq + r
                }
                ps += __shfl_xor(ps, 16);
                ps += __shfl_xor(ps, 32);
                lrun[half] += ps;
            }
            // ---- PV: V-frags shared by both q-halves, P straight from registers
#pragma unroll
            for (int dt = 0; dt < 8; ++dt) {
                int d = dt * 16 + lq;
                bf16x8 vf = *(const bf16x8*)&Vlds[buf][d * 32 + ((gq ^ ((d >> 1) & 3)) << 3)];
                acc[0][dt] = __builtin_amdgcn_mfma_f32_16x16x32_bf16(pf[0], vf, acc[0][dt], 0, 0, 0);
                acc[1][dt] = __builtin_amdgcn_mfma_f32_16x16x32_bf16(pf[1], vf, acc[1][dt], 0, 0, 0);
            }
        }
    }

    // ---- epilogue
#pragma unroll
    for (int half = 0; half < 2; ++half) {
        float il = 1.0f / lrun[half];
        float i0 = __shfl(il, gq * 4);
        float i1 = __shfl(il, gq * 4 + 1);
        float i2 = __shfl(il, gq * 4 + 2);
        float i3 = __shfl(il, gq * 4 + 3);
        float* ob = outg + (size_t)(b * 2048 + qbase + half * 16) * 4096u + h * 128;
#pragma unroll
        for (int dt = 0; dt < 8; ++dt) {
            ob[(size_t)(gq * 4 + 0) * 4096u + dt * 16 + lq] = acc[half][dt][0] * i0;
            ob[(size_t)(gq * 4 + 1) * 4096u + dt * 16 + lq] = acc[half][dt][1] * i1;
            ob[(size_t)(gq * 4 + 2) * 4096u + dt * 16 + lq] = acc[half][dt][2] * i2;
            ob[(size_t)(gq * 4 + 3) * 4096u + dt * 16 + lq] = acc[half][dt][3] * i3;
        }
    }
}

extern "C" void kernel_launch(void* const* d_in, const int* in_sizes, int n_in,
                              void* d_out, int out_size, void* d_ws, size_t ws_size,
                              hipStream_t stream) {
    const float* q = (const float*)d_in[0];
    const float* k = (const float*)d_in[1];
    const float* v = (const float*)d_in[2];
    float* out = (float*)d_out;
    unsigned short* kbuf = (unsigned short*)d_ws;                    // 8 MB bf16 K
    unsigned short* vbuf = kbuf + (size_t)2 * 8 * 2048 * 128;        // 8 MB bf16 V^T (tiled)
    cvt_k<<<2048, 256, 0, stream>>>(k, kbuf);
    cvt_v<<<2048, 256, 0, stream>>>(v, vbuf);
    attn_fwd<<<1024, 256, 0, stream>>>(q, kbuf, vbuf, out);
}

// Round 5
// 167.307 us; speedup vs baseline: 1.4846x; 1.0567x over previous
//
#include <hip/hip_runtime.h>
#include <stdint.h>

// Causal GQA attention fwd, B=2 T=2048 H=32 HKV=8 D=128, fp32 in/out, bf16 MFMA compute.
//
// Round 5: structural load balance. Each wave owns 16 q-rows of a LOW strip [64j, 64j+64)
// and 16 q-rows of the mirror HIGH strip [2048-64(j+1), 2048-64j). Low+high active-tile
// count is ~66 for every j => every block uniform work (was 1..16x spread). Low-half
// compute gated by wave-uniform lowActive. T5 setprio around MFMA clusters.
// Everything else = round 4 (zero-shuffle P via kv-permuted V^T, 32KB LDS, (256,3)).
//
//   cvt_k:  K fp32 [B,T,8,128] -> Kb bf16 [B,8,T,128], 16B-slot s stored at s^(t&7)
//   cvt_v:  V fp32 [B,T,8,128] -> VTb bf16 tiled [B,8,tile(64)][d(128)][slots], where
//           B-frag slot g elem e holds kv pi(8g+e) = (e<4 ? 4g+e : 16+4g+e-4); slot
//           stored at g^((d>>1)&3) for conflict-free ds_read_b128.
//   attn:   1024 blocks x 256 thr (4 waves). Block = (b, h, strip-pair j).
//           KV tiles of 32, double-buffered LDS staged via global_load_lds width=16.
//           QK^T swapped: S^T = mfma(K-frag, Q-frag)  (lane: q=lane&15, kv=(lane>>4)*4+reg)
//           Online softmax log2-domain, T13 defer-rescale (THR=8), diagonal-only masking.

typedef __attribute__((ext_vector_type(8))) __bf16 bf16x8;
typedef __attribute__((ext_vector_type(4))) float f32x4;

#define QSCALE (0.08838834764831845f * 1.4426950408889634f)

// ---------------- pre-pass: K convert + swizzle ----------------
__global__ __launch_bounds__(256) void cvt_k(const float* __restrict__ k,
                                             unsigned short* __restrict__ kb) {
    unsigned tid = blockIdx.x * 256u + threadIdx.x;
    unsigned s = tid & 15u;
    unsigned h = (tid >> 4) & 7u;
    unsigned t = (tid >> 7) & 2047u;
    unsigned b = tid >> 18;
    const float4* src = (const float4*)(k + (size_t)tid * 8u);
    float4 f0 = src[0], f1 = src[1];
    bf16x8 r;
    r[0] = (__bf16)f0.x; r[1] = (__bf16)f0.y; r[2] = (__bf16)f0.z; r[3] = (__bf16)f0.w;
    r[4] = (__bf16)f1.x; r[5] = (__bf16)f1.y; r[6] = (__bf16)f1.z; r[7] = (__bf16)f1.w;
    size_t o = ((size_t)((b * 8u + h) * 2048u + t) * 16u + (s ^ (t & 7u))) * 8u;
    *(bf16x8*)(kb + o) = r;
}

// ---------------- pre-pass: V convert + transpose + kv-permute + tile ----------------
__global__ __launch_bounds__(256) void cvt_v(const float* __restrict__ v,
                                             unsigned short* __restrict__ vtb) {
    unsigned tid = blockIdx.x * 256u + threadIdx.x;
    unsigned d = tid & 127u;            // fast-varying => coalesced reads
    unsigned slot = (tid >> 7) & 3u;    // B-fragment group g
    unsigned tile = (tid >> 9) & 63u;
    unsigned h = (tid >> 15) & 7u;
    unsigned b = tid >> 18;
    const float* src = v + ((size_t)(b * 2048u + tile * 32u) * 8u + h) * 128u + d;
    bf16x8 r;
#pragma unroll
    for (int jj = 0; jj < 8; ++jj) {
        unsigned kvl = (jj < 4) ? (slot * 4u + jj) : (12u + slot * 4u + jj); // pi(8g+e)
        r[jj] = (__bf16)src[(size_t)kvl * 1024u];
    }
    size_t o = (((size_t)((b * 8u + h) * 64u + tile) * 128u + d) * 4u
                + (slot ^ ((d >> 1) & 3u))) * 8u;
    *(bf16x8*)(vtb + o) = r;
}

// ---------------- main attention kernel ----------------
__device__ inline void load16_lds(const void* g, void* l) {
    __builtin_amdgcn_global_load_lds(
        (__attribute__((address_space(1))) void*)(g),
        (__attribute__((address_space(3))) void*)(l), 16, 0, 0);
}

__global__ __launch_bounds__(256, 3) void attn_fwd(const float* __restrict__ qg,
                                                   const unsigned short* __restrict__ kb,
                                                   const unsigned short* __restrict__ vtb,
                                                   float* __restrict__ outg) {
    __shared__ __align__(16) unsigned short Klds[2][32 * 128];   // 16 KB
    __shared__ __align__(16) unsigned short Vlds[2][128 * 32];   // 16 KB

    // Decode: bid&7 = XCD; each XCD owns one kvh (both b) -> 2MB KV in its L2.
    int bid = blockIdx.x;
    int x = bid & 7, ii = bid >> 3;            // ii: 0..127
    int g = x + 8 * (ii >> 6);                 // kv-group 0..15
    int rest = ii & 63;
    int b = g >> 3, kvh = g & 7;
    int h = kvh * 4 + (rest >> 4);
    int j = rest & 15;                         // strip-pair index

    int lane = threadIdx.x & 63;
    int w = threadIdx.x >> 6;
    int lq = lane & 15;
    int gq = lane >> 4;

    // half 0 = low strip, half 1 = high (mirror) strip; 16 rows each per wave.
    int qb[2];
    qb[0] = 64 * j + 16 * w;
    qb[1] = 2048 - 64 * (j + 1) + 16 * w;
    int nt = 64 - 2 * j;                       // kv tiles needed by the high strip

    const unsigned short* kTile = kb + (size_t)(b * 8 + kvh) * 2048u * 128u;
    const unsigned short* vTile = vtb + (size_t)(b * 8 + kvh) * 64u * 4096u;

    auto stage = [&](int t, int buf) {
        const char* ks = (const char*)(kTile + (size_t)t * 4096u);
        const char* vs = (const char*)(vTile + (size_t)t * 4096u);
#pragma unroll
        for (int c2 = 0; c2 < 2; ++c2) {
            int call = w * 2 + c2;
            load16_lds(ks + call * 1024 + lane * 16, &Klds[buf][call * 512]);
            load16_lds(vs + call * 1024 + lane * 16, &Vlds[buf][call * 512]);
        }
    };

    stage(0, 0);

    bf16x8 qf[2][4];
#pragma unroll
    for (int half = 0; half < 2; ++half) {
        const float* qp = qg + ((size_t)(b * 2048 + qb[half] + lq) * 32u + h) * 128u;
#pragma unroll
        for (int c = 0; c < 4; ++c) {
            const float4* p4 = (const float4*)(qp + c * 32 + gq * 8);
            float4 f0 = p4[0], f1 = p4[1];
            qf[half][c][0] = (__bf16)(f0.x * QSCALE); qf[half][c][1] = (__bf16)(f0.y * QSCALE);
            qf[half][c][2] = (__bf16)(f0.z * QSCALE); qf[half][c][3] = (__bf16)(f0.w * QSCALE);
            qf[half][c][4] = (__bf16)(f1.x * QSCALE); qf[half][c][5] = (__bf16)(f1.y * QSCALE);
            qf[half][c][6] = (__bf16)(f1.z * QSCALE); qf[half][c][7] = (__bf16)(f1.w * QSCALE);
        }
    }

    f32x4 zero4 = {0.f, 0.f, 0.f, 0.f};
    f32x4 acc[2][8];
#pragma unroll
    for (int half = 0; half < 2; ++half)
#pragma unroll
        for (int dt = 0; dt < 8; ++dt) acc[half][dt] = zero4;
    float mrun[2] = {-1e30f, -1e30f}, lrun[2] = {0.f, 0.f};

    for (int t = 0; t < nt; ++t) {
        asm volatile("s_waitcnt vmcnt(0)" ::: "memory");
        __syncthreads();
        int buf = t & 1;
        if (t + 1 < nt) stage(t + 1, buf ^ 1);
        int kv0 = t * 32;
        bool lowActive = (kv0 <= qb[0] + 15);            // wave-uniform
        if (kv0 <= qb[1] + 15) {                         // high strip active (superset)
            // ---- QK^T: K-frags shared; low half's MFMAs gated
            f32x4 st[2][2];
            st[0][0] = zero4; st[0][1] = zero4; st[1][0] = zero4; st[1][1] = zero4;
            int soff = lq & 7;
            __builtin_amdgcn_s_setprio(1);
            if (lowActive) {
#pragma unroll
                for (int c = 0; c < 4; ++c) {
                    bf16x8 kf0 = *(const bf16x8*)&Klds[buf][lq * 128 + (((c * 4 + gq) ^ soff) << 3)];
                    bf16x8 kf1 = *(const bf16x8*)&Klds[buf][(16 + lq) * 128 + (((c * 4 + gq) ^ soff) << 3)];
                    st[1][0] = __builtin_amdgcn_mfma_f32_16x16x32_bf16(kf0, qf[1][c], st[1][0], 0, 0, 0);
                    st[0][0] = __builtin_amdgcn_mfma_f32_16x16x32_bf16(kf0, qf[0][c], st[0][0], 0, 0, 0);
                    st[1][1] = __builtin_amdgcn_mfma_f32_16x16x32_bf16(kf1, qf[1][c], st[1][1], 0, 0, 0);
                    st[0][1] = __builtin_amdgcn_mfma_f32_16x16x32_bf16(kf1, qf[0][c], st[0][1], 0, 0, 0);
                }
            } else {
#pragma unroll
                for (int c = 0; c < 4; ++c) {
                    bf16x8 kf0 = *(const bf16x8*)&Klds[buf][lq * 128 + (((c * 4 + gq) ^ soff) << 3)];
                    bf16x8 kf1 = *(const bf16x8*)&Klds[buf][(16 + lq) * 128 + (((c * 4 + gq) ^ soff) << 3)];
                    st[1][0] = __builtin_amdgcn_mfma_f32_16x16x32_bf16(kf0, qf[1][c], st[1][0], 0, 0, 0);
                    st[1][1] = __builtin_amdgcn_mfma_f32_16x16x32_bf16(kf1, qf[1][c], st[1][1], 0, 0, 0);
                }
            }
            __builtin_amdgcn_s_setprio(0);
            // ---- mask (diagonal tiles only) + per-row max; per-half
            float mx[2] = {-1e30f, -1e30f};
            auto smax = [&](int half, f32x4* sth) {
                int qbh = qb[half];
                if (kv0 + 31 > qbh) {                    // wave-uniform diagonal check
                    int qr = qbh + lq;
#pragma unroll
                    for (int r = 0; r < 4; ++r) {
                        if (kv0 + gq * 4 + r > qr)      sth[0][r] = -1e30f;
                        if (kv0 + 16 + gq * 4 + r > qr) sth[1][r] = -1e30f;
                    }
                }
                float m = -1e30f;
#pragma unroll
                for (int r = 0; r < 4; ++r)
                    m = fmaxf(m, fmaxf(sth[0][r], sth[1][r]));
                m = fmaxf(m, __shfl_xor(m, 16));
                m = fmaxf(m, __shfl_xor(m, 32));
                mx[half] = m;
            };
            smax(1, st[1]);
            if (lowActive) smax(0, st[0]);
            // ---- T13 defer-rescale (mx[0] stays -1e30 when low inactive -> no-op there)
            if (!__all(mx[0] <= mrun[0] + 8.f && mx[1] <= mrun[1] + 8.f)) {
#pragma unroll
                for (int half = 0; half < 2; ++half) {
                    float mn = fmaxf(mrun[half], mx[half]);
                    float fac = exp2f(mrun[half] - mn);
                    lrun[half] *= fac; mrun[half] = mn;
                    float fr0 = __shfl(fac, gq * 4);
                    float fr1 = __shfl(fac, gq * 4 + 1);
                    float fr2 = __shfl(fac, gq * 4 + 2);
                    float fr3 = __shfl(fac, gq * 4 + 3);
#pragma unroll
                    for (int dt = 0; dt < 8; ++dt) {
                        acc[half][dt][0] *= fr0; acc[half][dt][1] *= fr1;
                        acc[half][dt][2] *= fr2; acc[half][dt][3] *= fr3;
                    }
                }
            }
            // ---- exp2, row-sum, pack P in-register (kv order matches permuted V^T)
            bf16x8 pf[2];
            auto packp = [&](int half, f32x4* sth) {
                float ps = 0.f;
#pragma unroll
                for (int r = 0; r < 4; ++r) {
                    float v0 = exp2f(sth[0][r] - mrun[half]);
                    float v1 = exp2f(sth[1][r] - mrun[half]);
                    ps += v0 + v1;
                    pf[half][r] = (__bf16)v0;       // kv = 4*gq + r
                    pf[half][4 + r] = (__bf16)v1;   // kv = 16 + 4*gq + r
                }
                ps += __shfl_xor(ps, 16);
                ps += __shfl_xor(ps, 32);
                lrun[half] += ps;
            };
            packp(1, st[1]);
            if (lowActive) packp(0, st[0]);
            // ---- PV: V-frags shared; low half gated
            __builtin_amdgcn_s_setprio(1);
            if (lowActive) {
#pragma unroll
                for (int dt = 0; dt < 8; ++dt) {
                    int d = dt * 16 + lq;
                    bf16x8 vf = *(const bf16x8*)&Vlds[buf][d * 32 + ((gq ^ ((d >> 1) & 3)) << 3)];
                    acc[1][dt] = __builtin_amdgcn_mfma_f32_16x16x32_bf16(pf[1], vf, acc[1][dt], 0, 0, 0);
                    acc[0][dt] = __builtin_amdgcn_mfma_f32_16x16x32_bf16(pf[0], vf, acc[0][dt], 0, 0, 0);
                }
            } else {
#pragma unroll
                for (int dt = 0; dt < 8; ++dt) {
                    int d = dt * 16 + lq;
                    bf16x8 vf = *(const bf16x8*)&Vlds[buf][d * 32 + ((gq ^ ((d >> 1) & 3)) << 3)];
                    acc[1][dt] = __builtin_amdgcn_mfma_f32_16x16x32_bf16(pf[1], vf, acc[1][dt], 0, 0, 0);
                }
            }
            __builtin_amdgcn_s_setprio(0);
        }
    }

    // ---- epilogue
#pragma unroll
    for (int half = 0; half < 2; ++half) {
        float il = 1.0f / lrun[half];
        float i0 = __shfl(il, gq * 4);
        float i1 = __shfl(il, gq * 4 + 1);
        float i2 = __shfl(il, gq * 4 + 2);
        float i3 = __shfl(il, gq * 4 + 3);
        float* ob = outg + (size_t)(b * 2048 + qb[half]) * 4096u + h * 128;
#pragma unroll
        for (int dt = 0; dt < 8; ++dt) {
            ob[(size_t)(gq * 4 + 0) * 4096u + dt * 16 + lq] = acc[half][dt][0] * i0;
            ob[(size_t)(gq * 4 + 1) * 4096u + dt * 16 + lq] = acc[half][dt][1] * i1;
            ob[(size_t)(gq * 4 + 2) * 4096u + dt * 16 + lq] = acc[half][dt][2] * i2;
            ob[(size_t)(gq * 4 + 3) * 4096u + dt * 16 + lq] = acc[half][dt][3] * i3;
        }
    }
}

extern "C" void kernel_launch(void* const* d_in, const int* in_sizes, int n_in,
                              void* d_out, int out_size, void* d_ws, size_t ws_size,
                              hipStream_t stream) {
    const float* q = (const float*)d_in[0];
    const float* k = (const float*)d_in[1];
    const float* v = (const float*)d_in[2];
    float* out = (float*)d_out;
    unsigned short* kbuf = (unsigned short*)d_ws;                    // 8 MB bf16 K
    unsigned short* vbuf = kbuf + (size_t)2 * 8 * 2048 * 128;        // 8 MB bf16 V^T (tiled)
    cvt_k<<<2048, 256, 0, stream>>>(k, kbuf);
    cvt_v<<<2048, 256, 0, stream>>>(v, vbuf);
    attn_fwd<<<1024, 256, 0, stream>>>(q, kbuf, vbuf, out);
}

// Round 6
// 138.632 us; speedup vs baseline: 1.7917x; 1.2068x over previous
//
#include <hip/hip_runtime.h>
#include <stdint.h>

// Causal GQA attention fwd, B=2 T=2048 H=32 HKV=8 D=128, fp32 in/out, bf16 MFMA compute.
//
// Round 6: 32x32x16 swapped structure. S^T = mfma(K,Q) has col=q=lane&31 => softmax
// max/sum = in-lane over 16 regs + one shfl_xor(32); m/l/fac/il lane-local (zero
// broadcast shuffles). P -> PV B-operand in-register via 4 shfl_xor(32)+selects per
// 32-kv subtile. KVBLK=64 (half the barriers), block = 4 waves x 32 q = 128 rows,
// LDS 64KB (2 blocks/CU), (256,2). LPT dispatch (qtile descending per XCD).
//
//   cvt_k:  K fp32 [B,T,8,128] -> Kb bf16 [B,8,T,128], 16B-slot s stored at s^(t&7)
//   cvt_v:  V fp32 [B,T,8,128] -> VTb bf16 [B,8,tile64][d:128][kv-octet slot: s^(d&7)]
//   attn:   1024 blocks x 256 thr. QK^T: A=K[kv32 x d16-chunk] row=lane&31,
//           k-octet=(lane>>5)*8; B=Q same k map. S^T col=q=lane&31,
//           row kv=(r&3)+8*(r>>2)+4*(lane>>5). PV: A=V^T[d32 x kv16], B=P^T in-reg.

typedef __attribute__((ext_vector_type(8))) __bf16 bf16x8;
typedef __attribute__((ext_vector_type(16))) float f32x16;

#define QSCALE (0.08838834764831845f * 1.4426950408889634f)

// ---------------- pre-pass: K convert + swizzle ----------------
__global__ __launch_bounds__(256) void cvt_k(const float* __restrict__ k,
                                             unsigned short* __restrict__ kb) {
    unsigned tid = blockIdx.x * 256u + threadIdx.x;
    unsigned s = tid & 15u;
    unsigned h = (tid >> 4) & 7u;
    unsigned t = (tid >> 7) & 2047u;
    unsigned b = tid >> 18;
    const float4* src = (const float4*)(k + (size_t)tid * 8u);
    float4 f0 = src[0], f1 = src[1];
    bf16x8 r;
    r[0] = (__bf16)f0.x; r[1] = (__bf16)f0.y; r[2] = (__bf16)f0.z; r[3] = (__bf16)f0.w;
    r[4] = (__bf16)f1.x; r[5] = (__bf16)f1.y; r[6] = (__bf16)f1.z; r[7] = (__bf16)f1.w;
    size_t o = ((size_t)((b * 8u + h) * 2048u + t) * 16u + (s ^ (t & 7u))) * 8u;
    *(bf16x8*)(kb + o) = r;
}

// ---------------- pre-pass: V convert + transpose + tile ----------------
// VTb layout: [b][h][tile(32 of 64kv)][d(128)][slot(8)][elem(8)], slot holds kv
// octet (slot*8..+8) of the tile, stored at slot ^ (d&7) for conflict-free b128.
__global__ __launch_bounds__(256) void cvt_v(const float* __restrict__ v,
                                             unsigned short* __restrict__ vtb) {
    unsigned tid = blockIdx.x * 256u + threadIdx.x;
    unsigned d = tid & 127u;
    unsigned slot = (tid >> 7) & 7u;
    unsigned tile = (tid >> 10) & 31u;
    unsigned h = (tid >> 15) & 7u;
    unsigned b = tid >> 18;
    const float* src = v + ((size_t)(b * 2048u + tile * 64u + slot * 8u) * 8u + h) * 128u + d;
    bf16x8 r;
#pragma unroll
    for (int j = 0; j < 8; ++j) r[j] = (__bf16)src[(size_t)j * 1024u];
    size_t o = (((size_t)((b * 8u + h) * 32u + tile) * 128u + d) * 8u + (slot ^ (d & 7u))) * 8u;
    *(bf16x8*)(vtb + o) = r;
}

// ---------------- main attention kernel ----------------
__device__ inline void load16_lds(const void* g, void* l) {
    __builtin_amdgcn_global_load_lds(
        (__attribute__((address_space(1))) void*)(g),
        (__attribute__((address_space(3))) void*)(l), 16, 0, 0);
}

union BW2 { unsigned u; __bf16 h[2]; };
union BW8 { unsigned u[4]; bf16x8 v; };

__global__ __launch_bounds__(256, 2) void attn_fwd(const float* __restrict__ qg,
                                                   const unsigned short* __restrict__ kb,
                                                   const unsigned short* __restrict__ vtb,
                                                   float* __restrict__ outg) {
    __shared__ __align__(16) unsigned short Klds[2][64 * 128];   // 32 KB
    __shared__ __align__(16) unsigned short Vlds[2][128 * 64];   // 32 KB

    // Decode: bid&7 = XCD = kvh; within XCD: b, then qtile DESCENDING (LPT), then head.
    int bid = blockIdx.x;
    int kvh = bid & 7;
    int ii = bid >> 3;                 // 0..127
    int b = ii >> 6;
    int rest = ii & 63;
    int qtile = 15 - (rest >> 2);
    int h = kvh * 4 + (rest & 3);
    int q0 = qtile * 128;

    int tid = threadIdx.x;
    int lane = tid & 63;
    int w = tid >> 6;
    int lq = lane & 31;
    int hi = lane >> 5;
    bool bhi = (hi != 0);
    int q0w = q0 + w * 32;
    int qmaxw = q0w + 31;
    int nt = 2 * (qtile + 1);

    const unsigned short* kTile = kb + (size_t)(b * 8 + kvh) * 2048u * 128u;
    const unsigned short* vTile = vtb + (size_t)(b * 8 + kvh) * 32u * 8192u;

    auto stage = [&](int t, int buf) {
        const char* ks = (const char*)(kTile + (size_t)t * 8192u);   // 16 KB contiguous
        const char* vs = (const char*)(vTile + (size_t)t * 8192u);   // 16 KB contiguous
#pragma unroll
        for (int i = 0; i < 4; ++i) {
            load16_lds(ks + (i * 256 + tid) * 16, &Klds[buf][(i * 256 + tid) * 8]);
            load16_lds(vs + (i * 256 + tid) * 16, &Vlds[buf][(i * 256 + tid) * 8]);
        }
    };

    stage(0, 0);

    // Q B-frags: lane holds q-row = q0w+lq, d-octet (lane>>5) of each 16-chunk.
    bf16x8 qf[8];
    {
        const float* qp = qg + ((size_t)(b * 2048 + q0w + lq) * 32u + h) * 128u;
#pragma unroll
        for (int c = 0; c < 8; ++c) {
            int d0 = c * 16 + hi * 8;
            float4 f0 = *(const float4*)(qp + d0);
            float4 f1 = *(const float4*)(qp + d0 + 4);
            qf[c][0] = (__bf16)(f0.x * QSCALE); qf[c][1] = (__bf16)(f0.y * QSCALE);
            qf[c][2] = (__bf16)(f0.z * QSCALE); qf[c][3] = (__bf16)(f0.w * QSCALE);
            qf[c][4] = (__bf16)(f1.x * QSCALE); qf[c][5] = (__bf16)(f1.y * QSCALE);
            qf[c][6] = (__bf16)(f1.z * QSCALE); qf[c][7] = (__bf16)(f1.w * QSCALE);
        }
    }

    f32x16 acc[4];
#pragma unroll
    for (int dt = 0; dt < 4; ++dt)
#pragma unroll
        for (int r = 0; r < 16; ++r) acc[dt][r] = 0.f;
    float mrun = -1e30f, lrun = 0.f;

    for (int t = 0; t < nt; ++t) {
        asm volatile("s_waitcnt vmcnt(0)" ::: "memory");
        __syncthreads();
        int buf = t & 1;
        if (t + 1 < nt) stage(t + 1, buf ^ 1);
        int kv0 = t * 64;
        if (kv0 <= qmaxw) {                          // wave-uniform
            bool s1a = (kv0 + 32 <= qmaxw);          // second 32-kv subtile active
            // ---- QK^T
            f32x16 st0, st1;
#pragma unroll
            for (int r = 0; r < 16; ++r) { st0[r] = 0.f; st1[r] = 0.f; }
            __builtin_amdgcn_s_setprio(1);
#pragma unroll
            for (int c = 0; c < 8; ++c) {
                int so = ((2 * c + hi) ^ (lq & 7)) << 3;
                bf16x8 kf0 = *(const bf16x8*)&Klds[buf][lq * 128 + so];
                st0 = __builtin_amdgcn_mfma_f32_32x32x16_bf16(kf0, qf[c], st0, 0, 0, 0);
            }
            if (s1a) {
#pragma unroll
                for (int c = 0; c < 8; ++c) {
                    int so = ((2 * c + hi) ^ (lq & 7)) << 3;
                    bf16x8 kf1 = *(const bf16x8*)&Klds[buf][(32 + lq) * 128 + so];
                    st1 = __builtin_amdgcn_mfma_f32_32x32x16_bf16(kf1, qf[c], st1, 0, 0, 0);
                }
            }
            __builtin_amdgcn_s_setprio(0);
            // ---- causal mask (diagonal tiles only); q = q0w+lq, kv row per reg
            int qg_ = q0w + lq;
            if (kv0 + 31 > q0w) {
#pragma unroll
                for (int r = 0; r < 16; ++r) {
                    int kvl = (r & 3) + 8 * (r >> 2) + 4 * hi;
                    if (kv0 + kvl > qg_) st0[r] = -1e30f;
                }
            }
            if (s1a && (kv0 + 63 > q0w)) {
#pragma unroll
                for (int r = 0; r < 16; ++r) {
                    int kvl = (r & 3) + 8 * (r >> 2) + 4 * hi;
                    if (kv0 + 32 + kvl > qg_) st1[r] = -1e30f;
                }
            }
            // ---- lane-local max (combine lane<->lane+32 once)
            float m = -1e30f;
#pragma unroll
            for (int r = 0; r < 16; ++r) m = fmaxf(m, st0[r]);
            if (s1a)
#pragma unroll
                for (int r = 0; r < 16; ++r) m = fmaxf(m, st1[r]);
            m = fmaxf(m, __shfl_xor(m, 32));
            // ---- T13 defer-rescale (lane-local fac, no broadcast)
            if (!__all(m <= mrun + 8.f)) {
                float mn = fmaxf(mrun, m);
                float fac = exp2f(mrun - mn);
                lrun *= fac; mrun = mn;
#pragma unroll
                for (int dt = 0; dt < 4; ++dt)
#pragma unroll
                    for (int r = 0; r < 16; ++r) acc[dt][r] *= fac;
            }
            // ---- exp2 + lane-local sum
            float ps = 0.f;
#pragma unroll
            for (int r = 0; r < 16; ++r) { st0[r] = exp2f(st0[r] - mrun); ps += st0[r]; }
            if (s1a)
#pragma unroll
                for (int r = 0; r < 16; ++r) { st1[r] = exp2f(st1[r] - mrun); ps += st1[r]; }
            ps += __shfl_xor(ps, 32);
            lrun += ps;
            // ---- PV per 32-kv subtile: pack P to bf16 words, exchange lane<->lane+32,
            //      feed as B-operand; A = V^T frags from LDS.
#pragma unroll
            for (int s = 0; s < 2; ++s) {
                if (s == 1 && !s1a) break;
                const f32x16& stv = (s == 0) ? st0 : st1;
                unsigned wv[8];
#pragma unroll
                for (int i = 0; i < 8; ++i) {
                    BW2 t2; t2.h[0] = (__bf16)stv[2 * i]; t2.h[1] = (__bf16)stv[2 * i + 1];
                    wv[i] = t2.u;
                }
                unsigned u0 = bhi ? wv[0] : wv[2]; u0 = __shfl_xor(u0, 32);
                unsigned u1 = bhi ? wv[1] : wv[3]; u1 = __shfl_xor(u1, 32);
                unsigned u2 = bhi ? wv[4] : wv[6]; u2 = __shfl_xor(u2, 32);
                unsigned u3 = bhi ? wv[5] : wv[7]; u3 = __shfl_xor(u3, 32);
                BW8 pb0, pb1;
                pb0.u[0] = bhi ? u0 : wv[0]; pb0.u[1] = bhi ? u1 : wv[1];
                pb0.u[2] = bhi ? wv[2] : u0; pb0.u[3] = bhi ? wv[3] : u1;
                pb1.u[0] = bhi ? u2 : wv[4]; pb1.u[1] = bhi ? u3 : wv[5];
                pb1.u[2] = bhi ? wv[6] : u2; pb1.u[3] = bhi ? wv[7] : u3;
                __builtin_amdgcn_s_setprio(1);
#pragma unroll
                for (int dt = 0; dt < 4; ++dt) {
                    int drow = dt * 32 + lq;
                    int so0 = (((4 * s + hi) ^ (drow & 7)) << 3);
                    int so1 = (((4 * s + 2 + hi) ^ (drow & 7)) << 3);
                    bf16x8 vf0 = *(const bf16x8*)&Vlds[buf][drow * 64 + so0];
                    acc[dt] = __builtin_amdgcn_mfma_f32_32x32x16_bf16(vf0, pb0.v, acc[dt], 0, 0, 0);
                    bf16x8 vf1 = *(const bf16x8*)&Vlds[buf][drow * 64 + so1];
                    acc[dt] = __builtin_amdgcn_mfma_f32_32x32x16_bf16(vf1, pb1.v, acc[dt], 0, 0, 0);
                }
                __builtin_amdgcn_s_setprio(0);
            }
        }
    }

    // ---- epilogue: lane-local 1/l, f32x4 stores (d-quads are consecutive)
    float il = 1.0f / lrun;
    float* ob = outg + ((size_t)(b * 2048 + q0w + lq) * 32u + h) * 128u;
#pragma unroll
    for (int dt = 0; dt < 4; ++dt)
#pragma unroll
        for (int rq = 0; rq < 4; ++rq) {
            int d = dt * 32 + rq * 8 + hi * 4;
            float4 o4 = { acc[dt][rq * 4 + 0] * il, acc[dt][rq * 4 + 1] * il,
                          acc[dt][rq * 4 + 2] * il, acc[dt][rq * 4 + 3] * il };
            *(float4*)(ob + d) = o4;
        }
}

extern "C" void kernel_launch(void* const* d_in, const int* in_sizes, int n_in,
                              void* d_out, int out_size, void* d_ws, size_t ws_size,
                              hipStream_t stream) {
    const float* q = (const float*)d_in[0];
    const float* k = (const float*)d_in[1];
    const float* v = (const float*)d_in[2];
    float* out = (float*)d_out;
    unsigned short* kbuf = (unsigned short*)d_ws;                    // 8 MB bf16 K
    unsigned short* vbuf = kbuf + (size_t)2 * 8 * 2048 * 128;        // 8 MB bf16 V^T (tiled)
    cvt_k<<<2048, 256, 0, stream>>>(k, kbuf);
    cvt_v<<<2048, 256, 0, stream>>>(v, vbuf);
    attn_fwd<<<1024, 256, 0, stream>>>(q, kbuf, vbuf, out);
}